// Round 5
// baseline (125.455 us; speedup 1.0000x reference)
//
#include <hip/hip_runtime.h>
#include <cstdint>
#include <cstddef>

#define NE 1024   // embedding dim
#define HS 64     // head size
#define TT 2048   // sequence length
#define BB 8      // batch

typedef short bf16x8 __attribute__((ext_vector_type(8)));
typedef float f32x4  __attribute__((ext_vector_type(4)));

// round-to-nearest-even f32 -> bf16 (bit pattern as ushort)
__device__ __forceinline__ unsigned short f2b(float f) {
    union { float f; uint32_t u; } v; v.f = f;
    uint32_t r = v.u + 0x7fffu + ((v.u >> 16) & 1u);
    return (unsigned short)(r >> 16);
}
__device__ __forceinline__ float b2f(unsigned short b) {
    union { uint32_t u; float f; } v; v.u = ((uint32_t)b) << 16;
    return v.f;
}

// ---------------------------------------------------------------------------
// Kernel 0: W = [Wq;Wk;Wv*0.125] (192x1024) -> MFMA B-fragments, split hi/lo.
// frag layout (16x16x32): lane L holds B[k=kcg*32+(L>>4)*8+j][col=ntg*16+(L&15)]
// ---------------------------------------------------------------------------
__global__ __launch_bounds__(256) void wprep_kernel(
    const float* __restrict__ Wq, const float* __restrict__ Wk,
    const float* __restrict__ Wv,
    unsigned short* __restrict__ whf, unsigned short* __restrict__ wlf)
{
    const int t   = blockIdx.x * 256 + threadIdx.x;   // 0..24575
    const int L   = t & 63;
    const int kcg = (t >> 6) & 31;
    const int ntg = t >> 11;                          // 0..11
    const int col = ntg * 16 + (L & 15);              // 0..191
    const int k0  = kcg * 32 + (L >> 4) * 8;

    const float* W;
    float scale = 1.f;
    if (col < 64)        W = Wq + (size_t)col * NE;
    else if (col < 128)  W = Wk + (size_t)(col - 64) * NE;
    else               { W = Wv + (size_t)(col - 128) * NE; scale = 0.125f; }

    bf16x8 h, l;
#pragma unroll
    for (int j = 0; j < 8; ++j) {
        const float f = W[k0 + j] * scale;
        const unsigned short hb = f2b(f);
        const unsigned short lb = f2b(f - b2f(hb));
        h[j] = (short)hb;
        l[j] = (short)lb;
    }
    *reinterpret_cast<bf16x8*>(whf + (size_t)t * 8) = h;
    *reinterpret_cast<bf16x8*>(wlf + (size_t)t * 8) = l;
}

// ---------------------------------------------------------------------------
// Kernel 1: projections via split-bf16 MFMA.
// Outputs: qh/ql, kh/kl row-major [B*T][64] bf16 (hi/lo split),
//          vT [B][64 h][T] bf16 (transposed, 0.125 folded).
// ---------------------------------------------------------------------------
__global__ __launch_bounds__(256) void proj_mfma(
    const float* __restrict__ x,
    const unsigned short* __restrict__ whf,
    const unsigned short* __restrict__ wlf,
    unsigned short* __restrict__ qh, unsigned short* __restrict__ ql,
    unsigned short* __restrict__ kh, unsigned short* __restrict__ kl,
    unsigned short* __restrict__ vT)
{
    __shared__ unsigned short xh[64 * 64];   // 8 KB, swizzled
    __shared__ unsigned short xl[64 * 64];   // 8 KB, swizzled

    const int tid  = threadIdx.x;
    const int L    = tid & 63;
    const int w    = tid >> 6;               // wave id 0..3
    const int row0 = blockIdx.x * 64;

    f32x4 acc[4][3];
#pragma unroll
    for (int mt = 0; mt < 4; ++mt)
#pragma unroll
        for (int nt = 0; nt < 3; ++nt)
#pragma unroll
            for (int r = 0; r < 4; ++r) acc[mt][nt][r] = 0.f;

    const int srow = tid >> 2;               // 0..63
    const int sk0  = (tid & 3) * 16;
    const float* xsrc = x + (size_t)(row0 + srow) * NE + sk0;

    for (int ks = 0; ks < 16; ++ks) {        // K loop, BK = 64
        __syncthreads();
        {
            const float4* s4 = reinterpret_cast<const float4*>(xsrc + ks * 64);
            float xv[16];
#pragma unroll
            for (int i = 0; i < 4; ++i) {
                const float4 f = s4[i];
                xv[4*i+0] = f.x; xv[4*i+1] = f.y; xv[4*i+2] = f.z; xv[4*i+3] = f.w;
            }
#pragma unroll
            for (int c = 0; c < 2; ++c) {
                bf16x8 hv, lv;
#pragma unroll
                for (int j = 0; j < 8; ++j) {
                    const float f = xv[c * 8 + j];
                    const unsigned short hb = f2b(f);
                    const unsigned short lb = f2b(f - b2f(hb));
                    hv[j] = (short)hb;
                    lv[j] = (short)lb;
                }
                const int kb16 = (tid & 3) * 2 + c;
                const int off  = srow * 64 + ((kb16 ^ (srow & 7)) << 3);
                *reinterpret_cast<bf16x8*>(&xh[off]) = hv;
                *reinterpret_cast<bf16x8*>(&xl[off]) = lv;
            }
        }
        __syncthreads();

#pragma unroll
        for (int kc = 0; kc < 2; ++kc) {
            bf16x8 ah[4], al[4];
#pragma unroll
            for (int mt = 0; mt < 4; ++mt) {
                const int r    = mt * 16 + (L & 15);
                const int kb16 = kc * 4 + (L >> 4);
                const int off  = r * 64 + ((kb16 ^ (r & 7)) << 3);
                ah[mt] = *reinterpret_cast<const bf16x8*>(&xh[off]);
                al[mt] = *reinterpret_cast<const bf16x8*>(&xl[off]);
            }
#pragma unroll
            for (int nt = 0; nt < 3; ++nt) {
                const size_t fidx =
                    ((size_t)((w * 3 + nt) * 32 + (ks * 2 + kc))) * 64 + L;
                const bf16x8 bh = *reinterpret_cast<const bf16x8*>(whf + fidx * 8);
                const bf16x8 bl = *reinterpret_cast<const bf16x8*>(wlf + fidx * 8);
#pragma unroll
                for (int mt = 0; mt < 4; ++mt) {
                    acc[mt][nt] = __builtin_amdgcn_mfma_f32_16x16x32_bf16(
                        ah[mt], bh, acc[mt][nt], 0, 0, 0);
                    acc[mt][nt] = __builtin_amdgcn_mfma_f32_16x16x32_bf16(
                        ah[mt], bl, acc[mt][nt], 0, 0, 0);
                    acc[mt][nt] = __builtin_amdgcn_mfma_f32_16x16x32_bf16(
                        al[mt], bh, acc[mt][nt], 0, 0, 0);
                }
            }
        }
    }

    // epilogue: C/D layout col=L&15, row=(L>>4)*4+reg
#pragma unroll
    for (int nt = 0; nt < 3; ++nt) {
        const int gc0 = w * 48 + nt * 16;
        const int lc  = L & 15;
#pragma unroll
        for (int mt = 0; mt < 4; ++mt) {
            const int t0g = row0 + mt * 16 + (L >> 4) * 4;   // row of reg 0
            if (gc0 < 128) {
                unsigned short* dh = (gc0 < 64) ? qh : kh;
                unsigned short* dl = (gc0 < 64) ? ql : kl;
                const int col = (gc0 & 63) + lc;
#pragma unroll
                for (int reg = 0; reg < 4; ++reg) {
                    const float val = acc[mt][nt][reg];
                    const unsigned short hb = f2b(val);
                    const unsigned short lb = f2b(val - b2f(hb));
                    dh[(size_t)(t0g + reg) * HS + col] = hb;
                    dl[(size_t)(t0g + reg) * HS + col] = lb;
                }
            } else {
                const int col  = (gc0 - 128) + lc;   // h index
                const int bat  = t0g >> 11;
                const int tloc = t0g & 2047;
                ushort4 pk;
                unsigned short* pp = reinterpret_cast<unsigned short*>(&pk);
#pragma unroll
                for (int reg = 0; reg < 4; ++reg)
                    pp[reg] = f2b(acc[mt][nt][reg]);
                *reinterpret_cast<ushort4*>(
                    &vT[((size_t)bat * HS + col) * TT + tloc]) = pk;
            }
        }
    }
}

// ---------------------------------------------------------------------------
// Kernel 2: MFMA causal attention, QBLK=16 rows/block, 512 thr = 8 waves.
// acc[16] f32x4 (wave w owns col-tiles w+8i); P (normalized bf16, swizzled)
// 16x2048 = 64 KB LDS; ~75 KB total -> 2 blocks/CU. A written in one
// coalesced non-temporal pass from P (incl. causal zeros); PV split across
// wave pairs + LDS reduce.
// ---------------------------------------------------------------------------
__global__ __launch_bounds__(512, 4) void attn_mfma(
    const unsigned short* __restrict__ qh, const unsigned short* __restrict__ ql,
    const unsigned short* __restrict__ kh, const unsigned short* __restrict__ kl,
    const unsigned short* __restrict__ vT,
    float* __restrict__ A, float* __restrict__ out)
{
    __shared__ unsigned short P[16 * TT];    // 64 KB, 16B-chunk XOR swizzle
    __shared__ float redm[8][16];
    __shared__ float reds[8][16];
    __shared__ float mrow[16];
    __shared__ float sinv[16];
    __shared__ float pacc[8][256];           // PV partials, 8 KB

    const int tid = threadIdx.x;
    const int L   = tid & 63;
    const int w   = tid >> 6;                // wave 0..7
    const int b   = blockIdx.x & 7;          // batch == XCD slot
    const int qt  = 127 - (blockIdx.x >> 3); // longest first
    const int Q0  = qt * 16;
    const int E   = Q0 + 16;                 // causal extent
    const int Ec  = (E + 31) & ~31;          // ceil to 32 (PV granularity)
    const int g   = L >> 4;
    const int l16 = L & 15;
    const size_t tbase = (size_t)b * TT;

    // ---- Q fragments (hi/lo) ----
    bf16x8 qfh[2], qfl[2];
#pragma unroll
    for (int kc = 0; kc < 2; ++kc) {
        const size_t off = (tbase + Q0 + l16) * HS + kc * 32 + g * 8;
        qfh[kc] = *reinterpret_cast<const bf16x8*>(qh + off);
        qfl[kc] = *reinterpret_cast<const bf16x8*>(ql + off);
    }

    // ---- QK^T (split bf16: hh + hl + lh) ----
    f32x4 acc[16];
#pragma unroll
    for (int i = 0; i < 16; ++i)
#pragma unroll
        for (int r = 0; r < 4; ++r) acc[i][r] = 0.f;

#pragma unroll
    for (int i = 0; i < 16; ++i) {
        const int k0 = (w + 8 * i) * 16;
        if (k0 < E) {
#pragma unroll
            for (int kc = 0; kc < 2; ++kc) {
                const size_t koff = (tbase + k0 + l16) * HS + kc * 32 + g * 8;
                const bf16x8 bh = *reinterpret_cast<const bf16x8*>(kh + koff);
                const bf16x8 bl = *reinterpret_cast<const bf16x8*>(kl + koff);
                acc[i] = __builtin_amdgcn_mfma_f32_16x16x32_bf16(
                    qfh[kc], bh, acc[i], 0, 0, 0);
                acc[i] = __builtin_amdgcn_mfma_f32_16x16x32_bf16(
                    qfh[kc], bl, acc[i], 0, 0, 0);
                acc[i] = __builtin_amdgcn_mfma_f32_16x16x32_bf16(
                    qfl[kc], bh, acc[i], 0, 0, 0);
            }
        }
    }

    // ---- causal mask + per-lane partial row max ----
    float pm[4];
#pragma unroll
    for (int r = 0; r < 4; ++r) pm[r] = -3e38f;

#pragma unroll
    for (int i = 0; i < 16; ++i) {
        const int k0 = (w + 8 * i) * 16;
        if (k0 < E) {
            const int col = k0 + l16;
            const int row = Q0 + g * 4;
#pragma unroll
            for (int r = 0; r < 4; ++r) {
                float s = acc[i][r];
                s = (col > row + r) ? -3e38f : s;
                acc[i][r] = s;
                pm[r] = fmaxf(pm[r], s);
            }
        }
    }
#pragma unroll
    for (int m = 1; m < 16; m <<= 1)
#pragma unroll
        for (int r = 0; r < 4; ++r)
            pm[r] = fmaxf(pm[r], __shfl_xor(pm[r], m, 64));
    if (l16 == 0)
#pragma unroll
        for (int r = 0; r < 4; ++r) redm[w][g * 4 + r] = pm[r];
    __syncthreads();
    if (tid < 16) {
        float m = -3e38f;
#pragma unroll
        for (int ww = 0; ww < 8; ++ww) m = fmaxf(m, redm[ww][tid]);
        mrow[tid] = m;
    }
    __syncthreads();
    float mr[4];
#pragma unroll
    for (int r = 0; r < 4; ++r) mr[r] = mrow[g * 4 + r];

    // ---- exp (f32, in regs) + partial row sums ----
    float ps[4];
#pragma unroll
    for (int r = 0; r < 4; ++r) ps[r] = 0.f;

#pragma unroll
    for (int i = 0; i < 16; ++i) {
        const int k0 = (w + 8 * i) * 16;
        if (k0 < E) {
#pragma unroll
            for (int r = 0; r < 4; ++r) {
                const float e = __expf(acc[i][r] - mr[r]);
                acc[i][r] = e;
                ps[r] += e;
            }
        }
    }
#pragma unroll
    for (int m = 1; m < 16; m <<= 1)
#pragma unroll
        for (int r = 0; r < 4; ++r)
            ps[r] += __shfl_xor(ps[r], m, 64);
    if (l16 == 0)
#pragma unroll
        for (int r = 0; r < 4; ++r) reds[w][g * 4 + r] = ps[r];
    __syncthreads();
    if (tid < 16) {
        float s = 0.f;
#pragma unroll
        for (int ww = 0; ww < 8; ++ww) s += reds[ww][tid];
        sinv[tid] = 1.f / s;
    }
    __syncthreads();
    float iv[4];
#pragma unroll
    for (int r = 0; r < 4; ++r) iv[r] = sinv[g * 4 + r];

    // ---- write P (normalized bf16, swizzled LDS); zero PV overhang tile ----
#pragma unroll
    for (int i = 0; i < 16; ++i) {
        const int k0 = (w + 8 * i) * 16;
        if (k0 < E) {
            const int col   = k0 + l16;
            const int chunk = col >> 3;
            const int cl    = col & 7;
#pragma unroll
            for (int r = 0; r < 4; ++r) {
                const int row = g * 4 + r;
                P[row * 2048 + ((chunk ^ (row & 7)) << 3) + cl] =
                    f2b(acc[i][r] * iv[r]);
            }
        } else if (k0 < Ec) {
            const int col   = k0 + l16;
            const int chunk = col >> 3;
            const int cl    = col & 7;
#pragma unroll
            for (int r = 0; r < 4; ++r) {
                const int row = g * 4 + r;
                P[row * 2048 + ((chunk ^ (row & 7)) << 3) + cl] = 0;
            }
        }
    }
    __syncthreads();

    // ---- PV partial: tile ht = w&3; wave pair splits the k range ----
    const int ht  = w & 3;
    const int nkk = Ec >> 5;
    const int nh  = nkk >> 1;
    const int kk0 = (w < 4) ? 0 : nh;
    const int kk1 = (w < 4) ? nh : nkk;

    f32x4 oacc;
#pragma unroll
    for (int r = 0; r < 4; ++r) oacc[r] = 0.f;

    const unsigned short* vbase = vT + ((size_t)b * HS + ht * 16 + l16) * TT;
    for (int kk = kk0; kk < kk1; ++kk) {
        const int chunk = kk * 4 + g;
        const bf16x8 pa = *reinterpret_cast<const bf16x8*>(
            &P[l16 * 2048 + ((chunk ^ (l16 & 7)) << 3)]);
        const bf16x8 vb =
            *reinterpret_cast<const bf16x8*>(vbase + kk * 32 + g * 8);
        oacc = __builtin_amdgcn_mfma_f32_16x16x32_bf16(pa, vb, oacc, 0, 0, 0);
    }
#pragma unroll
    for (int r = 0; r < 4; ++r)
        pacc[w][(g * 4 + r) * 16 + l16] = oacc[r];
    __syncthreads();

    // ---- combine PV partials, store out (tiny) ----
    {
        const int e0  = tid * 2;
        const int row = e0 >> 6;              // 0..15
        const int h2  = e0 & 63;              // even
        const int ht2 = h2 >> 4;
        const int el  = h2 & 15;
        float2 o;
        o.x = pacc[ht2][row * 16 + el]     + pacc[ht2 + 4][row * 16 + el];
        o.y = pacc[ht2][row * 16 + el + 1] + pacc[ht2 + 4][row * 16 + el + 1];
        *reinterpret_cast<float2*>(&out[(tbase + Q0 + row) * HS + h2]) = o;
    }

    // ---- A write: coalesced non-temporal f32 pass from P (zeros beyond E) ----
#pragma unroll
    for (int rr = 0; rr < 2; ++rr) {
        const int row = 2 * w + rr;
        float* arow = A + (tbase + Q0 + row) * TT;
#pragma unroll
        for (int c0 = 0; c0 < TT; c0 += 256) {
            const int col = c0 + 4 * L;
            f32x4 o;
            if (col < E) {                    // col%4==0, E%16==0 -> col+3 < E
                const int chunk = col >> 3;
                const ushort4 pk = *reinterpret_cast<const ushort4*>(
                    &P[row * 2048 + ((chunk ^ (row & 7)) << 3) + (col & 7)]);
                o[0] = b2f(pk.x); o[1] = b2f(pk.y);
                o[2] = b2f(pk.z); o[3] = b2f(pk.w);
            } else {
                o[0] = 0.f; o[1] = 0.f; o[2] = 0.f; o[3] = 0.f;
            }
            __builtin_nontemporal_store(o, reinterpret_cast<f32x4*>(arow + col));
        }
    }
}

// ---------------------------------------------------------------------------
extern "C" void kernel_launch(void* const* d_in, const int* in_sizes, int n_in,
                              void* d_out, int out_size, void* d_ws,
                              size_t ws_size, hipStream_t stream)
{
    (void)in_sizes; (void)n_in; (void)out_size; (void)ws_size;

    // setup_inputs() dict order: x, Wk, Wq, Wv
    const float* x  = (const float*)d_in[0];
    const float* Wk = (const float*)d_in[1];
    const float* Wq = (const float*)d_in[2];
    const float* Wv = (const float*)d_in[3];

    float* A   = (float*)d_out;                         // (B,T,T)
    float* out = A + (size_t)BB * TT * TT;              // (B,T,H)

    // workspace: 5 bf16 arrays of B*T*H + W fragments  (10.75 MB total)
    const size_t NTH = (size_t)BB * TT * HS;            // 1048576
    unsigned short* qh  = (unsigned short*)d_ws;
    unsigned short* ql  = qh + NTH;
    unsigned short* kh  = ql + NTH;
    unsigned short* kl  = kh + NTH;
    unsigned short* vT  = kl + NTH;
    unsigned short* whf = vT + NTH;
    unsigned short* wlf = whf + (size_t)24576 * 8;

    wprep_kernel<<<96, 256, 0, stream>>>(Wq, Wk, Wv, whf, wlf);
    proj_mfma<<<256, 256, 0, stream>>>(x, whf, wlf, qh, ql, kh, kl, vT);
    attn_mfma<<<BB * (TT / 16), 512, 0, stream>>>(qh, ql, kh, kl, vT, A, out);
}

// Round 6
// 119.419 us; speedup vs baseline: 1.0505x; 1.0505x over previous
//
#include <hip/hip_runtime.h>
#include <cstdint>
#include <cstddef>

#define NE 1024   // embedding dim
#define HS 64     // head size
#define TT 2048   // sequence length
#define BB 8      // batch

typedef short bf16x8 __attribute__((ext_vector_type(8)));
typedef float f32x4  __attribute__((ext_vector_type(4)));

// round-to-nearest-even f32 -> bf16 (bit pattern as ushort)
__device__ __forceinline__ unsigned short f2b(float f) {
    union { float f; uint32_t u; } v; v.f = f;
    uint32_t r = v.u + 0x7fffu + ((v.u >> 16) & 1u);
    return (unsigned short)(r >> 16);
}
__device__ __forceinline__ float b2f(unsigned short b) {
    union { uint32_t u; float f; } v; v.u = ((uint32_t)b) << 16;
    return v.f;
}

// ---------------------------------------------------------------------------
// Kernel 0: W = [Wq;Wk;Wv*0.125] (192x1024) -> MFMA B-fragments, split hi/lo.
// frag layout (16x16x32): lane L holds B[k=kcg*32+(L>>4)*8+j][col=ntg*16+(L&15)]
// ---------------------------------------------------------------------------
__global__ __launch_bounds__(256) void wprep_kernel(
    const float* __restrict__ Wq, const float* __restrict__ Wk,
    const float* __restrict__ Wv,
    unsigned short* __restrict__ whf, unsigned short* __restrict__ wlf)
{
    const int t   = blockIdx.x * 256 + threadIdx.x;   // 0..24575
    const int L   = t & 63;
    const int kcg = (t >> 6) & 31;
    const int ntg = t >> 11;                          // 0..11
    const int col = ntg * 16 + (L & 15);              // 0..191
    const int k0  = kcg * 32 + (L >> 4) * 8;

    const float* W;
    float scale = 1.f;
    if (col < 64)        W = Wq + (size_t)col * NE;
    else if (col < 128)  W = Wk + (size_t)(col - 64) * NE;
    else               { W = Wv + (size_t)(col - 128) * NE; scale = 0.125f; }

    bf16x8 h, l;
#pragma unroll
    for (int j = 0; j < 8; ++j) {
        const float f = W[k0 + j] * scale;
        const unsigned short hb = f2b(f);
        const unsigned short lb = f2b(f - b2f(hb));
        h[j] = (short)hb;
        l[j] = (short)lb;
    }
    *reinterpret_cast<bf16x8*>(whf + (size_t)t * 8) = h;
    *reinterpret_cast<bf16x8*>(wlf + (size_t)t * 8) = l;
}

// ---------------------------------------------------------------------------
// Kernel 1: projections via split-bf16 MFMA.
// Outputs: qh/ql, kh/kl row-major [B*T][64] bf16 (hi/lo split),
//          vT [B][64 h][T] bf16 (transposed, 0.125 folded).
// ---------------------------------------------------------------------------
__global__ __launch_bounds__(256) void proj_mfma(
    const float* __restrict__ x,
    const unsigned short* __restrict__ whf,
    const unsigned short* __restrict__ wlf,
    unsigned short* __restrict__ qh, unsigned short* __restrict__ ql,
    unsigned short* __restrict__ kh, unsigned short* __restrict__ kl,
    unsigned short* __restrict__ vT)
{
    __shared__ unsigned short xh[64 * 64];   // 8 KB, swizzled
    __shared__ unsigned short xl[64 * 64];   // 8 KB, swizzled

    const int tid  = threadIdx.x;
    const int L    = tid & 63;
    const int w    = tid >> 6;               // wave id 0..3
    const int row0 = blockIdx.x * 64;

    f32x4 acc[4][3];
#pragma unroll
    for (int mt = 0; mt < 4; ++mt)
#pragma unroll
        for (int nt = 0; nt < 3; ++nt)
#pragma unroll
            for (int r = 0; r < 4; ++r) acc[mt][nt][r] = 0.f;

    const int srow = tid >> 2;               // 0..63
    const int sk0  = (tid & 3) * 16;
    const float* xsrc = x + (size_t)(row0 + srow) * NE + sk0;

    for (int ks = 0; ks < 16; ++ks) {        // K loop, BK = 64
        __syncthreads();
        {
            const float4* s4 = reinterpret_cast<const float4*>(xsrc + ks * 64);
            float xv[16];
#pragma unroll
            for (int i = 0; i < 4; ++i) {
                const float4 f = s4[i];
                xv[4*i+0] = f.x; xv[4*i+1] = f.y; xv[4*i+2] = f.z; xv[4*i+3] = f.w;
            }
#pragma unroll
            for (int c = 0; c < 2; ++c) {
                bf16x8 hv, lv;
#pragma unroll
                for (int j = 0; j < 8; ++j) {
                    const float f = xv[c * 8 + j];
                    const unsigned short hb = f2b(f);
                    const unsigned short lb = f2b(f - b2f(hb));
                    hv[j] = (short)hb;
                    lv[j] = (short)lb;
                }
                const int kb16 = (tid & 3) * 2 + c;
                const int off  = srow * 64 + ((kb16 ^ (srow & 7)) << 3);
                *reinterpret_cast<bf16x8*>(&xh[off]) = hv;
                *reinterpret_cast<bf16x8*>(&xl[off]) = lv;
            }
        }
        __syncthreads();

#pragma unroll
        for (int kc = 0; kc < 2; ++kc) {
            bf16x8 ah[4], al[4];
#pragma unroll
            for (int mt = 0; mt < 4; ++mt) {
                const int r    = mt * 16 + (L & 15);
                const int kb16 = kc * 4 + (L >> 4);
                const int off  = r * 64 + ((kb16 ^ (r & 7)) << 3);
                ah[mt] = *reinterpret_cast<const bf16x8*>(&xh[off]);
                al[mt] = *reinterpret_cast<const bf16x8*>(&xl[off]);
            }
#pragma unroll
            for (int nt = 0; nt < 3; ++nt) {
                const size_t fidx =
                    ((size_t)((w * 3 + nt) * 32 + (ks * 2 + kc))) * 64 + L;
                const bf16x8 bh = *reinterpret_cast<const bf16x8*>(whf + fidx * 8);
                const bf16x8 bl = *reinterpret_cast<const bf16x8*>(wlf + fidx * 8);
#pragma unroll
                for (int mt = 0; mt < 4; ++mt) {
                    acc[mt][nt] = __builtin_amdgcn_mfma_f32_16x16x32_bf16(
                        ah[mt], bh, acc[mt][nt], 0, 0, 0);
                    acc[mt][nt] = __builtin_amdgcn_mfma_f32_16x16x32_bf16(
                        ah[mt], bl, acc[mt][nt], 0, 0, 0);
                    acc[mt][nt] = __builtin_amdgcn_mfma_f32_16x16x32_bf16(
                        al[mt], bh, acc[mt][nt], 0, 0, 0);
                }
            }
        }
    }

    // epilogue: C/D layout col=L&15, row=(L>>4)*4+reg
#pragma unroll
    for (int nt = 0; nt < 3; ++nt) {
        const int gc0 = w * 48 + nt * 16;
        const int lc  = L & 15;
#pragma unroll
        for (int mt = 0; mt < 4; ++mt) {
            const int t0g = row0 + mt * 16 + (L >> 4) * 4;   // row of reg 0
            if (gc0 < 128) {
                unsigned short* dh = (gc0 < 64) ? qh : kh;
                unsigned short* dl = (gc0 < 64) ? ql : kl;
                const int col = (gc0 & 63) + lc;
#pragma unroll
                for (int reg = 0; reg < 4; ++reg) {
                    const float val = acc[mt][nt][reg];
                    const unsigned short hb = f2b(val);
                    const unsigned short lb = f2b(val - b2f(hb));
                    dh[(size_t)(t0g + reg) * HS + col] = hb;
                    dl[(size_t)(t0g + reg) * HS + col] = lb;
                }
            } else {
                const int col  = (gc0 - 128) + lc;   // h index
                const int bat  = t0g >> 11;
                const int tloc = t0g & 2047;
                ushort4 pk;
                unsigned short* pp = reinterpret_cast<unsigned short*>(&pk);
#pragma unroll
                for (int reg = 0; reg < 4; ++reg)
                    pp[reg] = f2b(acc[mt][nt][reg]);
                *reinterpret_cast<ushort4*>(
                    &vT[((size_t)bat * HS + col) * TT + tloc]) = pk;
            }
        }
    }
}

// ---------------------------------------------------------------------------
// Kernel 2: MFMA causal attention, QBLK=32 rows/block (round-3 structure),
// 512 thr = 8 waves. Wave w owns score col-tiles w+8i (acc[16][2] f32x4).
// Softmax via shfl + LDS cross-wave reduce. P (normalized bf16, swizzled)
// in 128 KB LDS. After one barrier: PV (wave-private out tile, MFMA with
// vT B-frags from L2) then a single coalesced non-temporal A f32 pass
// from P (values + causal zeros in one stream).
// ---------------------------------------------------------------------------
__global__ __launch_bounds__(512, 2) void attn_mfma(
    const unsigned short* __restrict__ qh, const unsigned short* __restrict__ ql,
    const unsigned short* __restrict__ kh, const unsigned short* __restrict__ kl,
    const unsigned short* __restrict__ vT,
    float* __restrict__ A, float* __restrict__ out)
{
    __shared__ unsigned short P[32 * TT];    // 128 KB, 16B-chunk XOR swizzle
    __shared__ float redm[8][32];
    __shared__ float reds[8][32];
    __shared__ float mrow[32];
    __shared__ float sinv[32];

    const int tid = threadIdx.x;
    const int L   = tid & 63;
    const int w   = tid >> 6;                // wave 0..7
    const int b   = blockIdx.x & 7;          // batch == XCD slot
    const int qt  = 63 - (blockIdx.x >> 3);  // longest first
    const int Q0  = qt * 32;
    const int E   = Q0 + 32;                 // causal extent (mult of 32)
    const int g   = L >> 4;
    const int l16 = L & 15;
    const size_t tbase = (size_t)b * TT;

    // ---- Q fragments (hi/lo) ----
    bf16x8 qfh[2][2], qfl[2][2];             // [rowtile][kchunk]
#pragma unroll
    for (int rt = 0; rt < 2; ++rt)
#pragma unroll
        for (int kc = 0; kc < 2; ++kc) {
            const size_t off = (tbase + Q0 + rt * 16 + l16) * HS + kc * 32 + g * 8;
            qfh[rt][kc] = *reinterpret_cast<const bf16x8*>(qh + off);
            qfl[rt][kc] = *reinterpret_cast<const bf16x8*>(ql + off);
        }

    // ---- QK^T (split bf16: hh + hl + lh) ----
    f32x4 acc[16][2];
#pragma unroll
    for (int i = 0; i < 16; ++i)
#pragma unroll
        for (int rt = 0; rt < 2; ++rt)
#pragma unroll
            for (int r = 0; r < 4; ++r) acc[i][rt][r] = 0.f;

#pragma unroll
    for (int i = 0; i < 16; ++i) {
        const int k0 = (w + 8 * i) * 16;
        if (k0 < E) {
#pragma unroll
            for (int kc = 0; kc < 2; ++kc) {
                const size_t koff = (tbase + k0 + l16) * HS + kc * 32 + g * 8;
                const bf16x8 bh = *reinterpret_cast<const bf16x8*>(kh + koff);
                const bf16x8 bl = *reinterpret_cast<const bf16x8*>(kl + koff);
#pragma unroll
                for (int rt = 0; rt < 2; ++rt) {
                    acc[i][rt] = __builtin_amdgcn_mfma_f32_16x16x32_bf16(
                        qfh[rt][kc], bh, acc[i][rt], 0, 0, 0);
                    acc[i][rt] = __builtin_amdgcn_mfma_f32_16x16x32_bf16(
                        qfh[rt][kc], bl, acc[i][rt], 0, 0, 0);
                    acc[i][rt] = __builtin_amdgcn_mfma_f32_16x16x32_bf16(
                        qfl[rt][kc], bh, acc[i][rt], 0, 0, 0);
                }
            }
        }
    }

    // ---- causal mask + per-lane partial row max ----
    float pm[2][4];
#pragma unroll
    for (int rt = 0; rt < 2; ++rt)
#pragma unroll
        for (int r = 0; r < 4; ++r) pm[rt][r] = -3e38f;

#pragma unroll
    for (int i = 0; i < 16; ++i) {
        const int k0 = (w + 8 * i) * 16;
        if (k0 < E) {
            const int col = k0 + l16;
#pragma unroll
            for (int rt = 0; rt < 2; ++rt) {
                const int row = Q0 + rt * 16 + g * 4;
#pragma unroll
                for (int r = 0; r < 4; ++r) {
                    float s = acc[i][rt][r];
                    s = (col > row + r) ? -3e38f : s;
                    acc[i][rt][r] = s;
                    pm[rt][r] = fmaxf(pm[rt][r], s);
                }
            }
        }
    }
#pragma unroll
    for (int m = 1; m < 16; m <<= 1)
#pragma unroll
        for (int rt = 0; rt < 2; ++rt)
#pragma unroll
            for (int r = 0; r < 4; ++r)
                pm[rt][r] = fmaxf(pm[rt][r], __shfl_xor(pm[rt][r], m, 64));
    if (l16 == 0)
#pragma unroll
        for (int rt = 0; rt < 2; ++rt)
#pragma unroll
            for (int r = 0; r < 4; ++r)
                redm[w][rt * 16 + g * 4 + r] = pm[rt][r];
    __syncthreads();
    if (tid < 32) {
        float m = -3e38f;
#pragma unroll
        for (int ww = 0; ww < 8; ++ww) m = fmaxf(m, redm[ww][tid]);
        mrow[tid] = m;
    }
    __syncthreads();
    float mr[2][4];
#pragma unroll
    for (int rt = 0; rt < 2; ++rt)
#pragma unroll
        for (int r = 0; r < 4; ++r) mr[rt][r] = mrow[rt * 16 + g * 4 + r];

    // ---- exp (f32, in regs) + partial row sums ----
    float ps[2][4];
#pragma unroll
    for (int rt = 0; rt < 2; ++rt)
#pragma unroll
        for (int r = 0; r < 4; ++r) ps[rt][r] = 0.f;

#pragma unroll
    for (int i = 0; i < 16; ++i) {
        const int k0 = (w + 8 * i) * 16;
        if (k0 < E) {
#pragma unroll
            for (int rt = 0; rt < 2; ++rt)
#pragma unroll
                for (int r = 0; r < 4; ++r) {
                    const float e = __expf(acc[i][rt][r] - mr[rt][r]);
                    acc[i][rt][r] = e;
                    ps[rt][r] += e;
                }
        }
    }
#pragma unroll
    for (int m = 1; m < 16; m <<= 1)
#pragma unroll
        for (int rt = 0; rt < 2; ++rt)
#pragma unroll
            for (int r = 0; r < 4; ++r)
                ps[rt][r] += __shfl_xor(ps[rt][r], m, 64);
    if (l16 == 0)
#pragma unroll
        for (int rt = 0; rt < 2; ++rt)
#pragma unroll
            for (int r = 0; r < 4; ++r)
                reds[w][rt * 16 + g * 4 + r] = ps[rt][r];
    __syncthreads();
    if (tid < 32) {
        float s = 0.f;
#pragma unroll
        for (int ww = 0; ww < 8; ++ww) s += reds[ww][tid];
        sinv[tid] = 1.f / s;
    }
    __syncthreads();
    float iv[2][4];
#pragma unroll
    for (int rt = 0; rt < 2; ++rt)
#pragma unroll
        for (int r = 0; r < 4; ++r) iv[rt][r] = sinv[rt * 16 + g * 4 + r];

    // ---- write P (normalized bf16, swizzled LDS) ----
#pragma unroll
    for (int i = 0; i < 16; ++i) {
        const int k0 = (w + 8 * i) * 16;
        if (k0 < E) {
            const int col   = k0 + l16;
            const int chunk = col >> 3;
            const int cl    = col & 7;
#pragma unroll
            for (int rt = 0; rt < 2; ++rt) {
                const int lrow = rt * 16 + g * 4;
#pragma unroll
                for (int r = 0; r < 4; ++r) {
                    const int row = lrow + r;
                    P[row * 2048 + ((chunk ^ (row & 7)) << 3) + cl] =
                        f2b(acc[i][rt][r] * iv[rt][r]);
                }
            }
        }
    }
    __syncthreads();

    // ---- PV: wave w owns out tile (rt_o = w>>2, ht = w&3); E%32==0 ----
    const int rt_o = w >> 2;
    const int ht   = w & 3;
    f32x4 oacc;
#pragma unroll
    for (int r = 0; r < 4; ++r) oacc[r] = 0.f;

    const int nkk = E >> 5;
    const unsigned short* vbase = vT + ((size_t)b * HS + ht * 16 + l16) * TT;
    const int prow = rt_o * 16 + l16;
    for (int kk = 0; kk < nkk; ++kk) {
        const int chunk = kk * 4 + g;
        const bf16x8 pa = *reinterpret_cast<const bf16x8*>(
            &P[prow * 2048 + ((chunk ^ (prow & 7)) << 3)]);
        const bf16x8 vb =
            *reinterpret_cast<const bf16x8*>(vbase + kk * 32 + g * 8);
        oacc = __builtin_amdgcn_mfma_f32_16x16x32_bf16(pa, vb, oacc, 0, 0, 0);
    }
#pragma unroll
    for (int r = 0; r < 4; ++r)
        out[(tbase + Q0 + rt_o * 16 + g * 4 + r) * HS + ht * 16 + l16] =
            oacc[r];

    // ---- A write: coalesced non-temporal f32 pass from P (zeros beyond E) ----
#pragma unroll
    for (int rr = 0; rr < 4; ++rr) {
        const int row = 4 * w + rr;
        float* arow = A + (tbase + Q0 + row) * TT;
#pragma unroll
        for (int c0 = 0; c0 < TT; c0 += 256) {
            const int col = c0 + 4 * L;
            f32x4 o;
            if (col < E) {                    // col%4==0, E%32==0 -> col+3 < E
                const int chunk = col >> 3;
                const ushort4 pk = *reinterpret_cast<const ushort4*>(
                    &P[row * 2048 + ((chunk ^ (row & 7)) << 3) + (col & 7)]);
                o[0] = b2f(pk.x); o[1] = b2f(pk.y);
                o[2] = b2f(pk.z); o[3] = b2f(pk.w);
            } else {
                o[0] = 0.f; o[1] = 0.f; o[2] = 0.f; o[3] = 0.f;
            }
            __builtin_nontemporal_store(o, reinterpret_cast<f32x4*>(arow + col));
        }
    }
}

// ---------------------------------------------------------------------------
extern "C" void kernel_launch(void* const* d_in, const int* in_sizes, int n_in,
                              void* d_out, int out_size, void* d_ws,
                              size_t ws_size, hipStream_t stream)
{
    (void)in_sizes; (void)n_in; (void)out_size; (void)ws_size;

    // setup_inputs() dict order: x, Wk, Wq, Wv
    const float* x  = (const float*)d_in[0];
    const float* Wk = (const float*)d_in[1];
    const float* Wq = (const float*)d_in[2];
    const float* Wv = (const float*)d_in[3];

    float* A   = (float*)d_out;                         // (B,T,T)
    float* out = A + (size_t)BB * TT * TT;              // (B,T,H)

    // workspace: 5 bf16 arrays of B*T*H + W fragments  (10.75 MB total)
    const size_t NTH = (size_t)BB * TT * HS;            // 1048576
    unsigned short* qh  = (unsigned short*)d_ws;
    unsigned short* ql  = qh + NTH;
    unsigned short* kh  = ql + NTH;
    unsigned short* kl  = kh + NTH;
    unsigned short* vT  = kl + NTH;
    unsigned short* whf = vT + NTH;
    unsigned short* wlf = whf + (size_t)24576 * 8;

    wprep_kernel<<<96, 256, 0, stream>>>(Wq, Wk, Wv, whf, wlf);
    proj_mfma<<<256, 256, 0, stream>>>(x, whf, wlf, qh, ql, kh, kl, vT);
    attn_mfma<<<BB * (TT / 32), 512, 0, stream>>>(qh, ql, kh, kl, vT, A, out);
}

// Round 7
// 117.951 us; speedup vs baseline: 1.0636x; 1.0124x over previous
//
#include <hip/hip_runtime.h>
#include <cstdint>
#include <cstddef>

#define NE 1024   // embedding dim
#define HS 64     // head size
#define TT 2048   // sequence length
#define BB 8      // batch

typedef short bf16x8 __attribute__((ext_vector_type(8)));
typedef float f32x4  __attribute__((ext_vector_type(4)));

// round-to-nearest-even f32 -> bf16 (bit pattern as ushort)
__device__ __forceinline__ unsigned short f2b(float f) {
    union { float f; uint32_t u; } v; v.f = f;
    uint32_t r = v.u + 0x7fffu + ((v.u >> 16) & 1u);
    return (unsigned short)(r >> 16);
}
__device__ __forceinline__ float b2f(unsigned short b) {
    union { uint32_t u; float f; } v; v.u = ((uint32_t)b) << 16;
    return v.f;
}

// ---------------------------------------------------------------------------
// Kernel 0: W = [Wq;Wk;Wv*0.125] (192x1024) -> MFMA B-fragments, split hi/lo.
// frag layout (16x16x32): lane L holds B[k=kcg*32+(L>>4)*8+j][col=ntg*16+(L&15)]
// ---------------------------------------------------------------------------
__global__ __launch_bounds__(256) void wprep_kernel(
    const float* __restrict__ Wq, const float* __restrict__ Wk,
    const float* __restrict__ Wv,
    unsigned short* __restrict__ whf, unsigned short* __restrict__ wlf)
{
    const int t   = blockIdx.x * 256 + threadIdx.x;   // 0..24575
    const int L   = t & 63;
    const int kcg = (t >> 6) & 31;
    const int ntg = t >> 11;                          // 0..11
    const int col = ntg * 16 + (L & 15);              // 0..191
    const int k0  = kcg * 32 + (L >> 4) * 8;

    const float* W;
    float scale = 1.f;
    if (col < 64)        W = Wq + (size_t)col * NE;
    else if (col < 128)  W = Wk + (size_t)(col - 64) * NE;
    else               { W = Wv + (size_t)(col - 128) * NE; scale = 0.125f; }

    bf16x8 h, l;
#pragma unroll
    for (int j = 0; j < 8; ++j) {
        const float f = W[k0 + j] * scale;
        const unsigned short hb = f2b(f);
        const unsigned short lb = f2b(f - b2f(hb));
        h[j] = (short)hb;
        l[j] = (short)lb;
    }
    *reinterpret_cast<bf16x8*>(whf + (size_t)t * 8) = h;
    *reinterpret_cast<bf16x8*>(wlf + (size_t)t * 8) = l;
}

// ---------------------------------------------------------------------------
// Kernel 1: projections via split-bf16 MFMA.
// 512 threads = 8 waves (2/SIMD for latency hiding); wave owns 2 m-tiles x
// 3 n-tiles (acc = 24 VGPR). Register prefetch of next x-subtile overlaps
// the MFMA phase. Outputs: qh/ql, kh/kl row-major bf16 (hi/lo split),
// vT [B][64 h][T] bf16 (transposed, 0.125 folded).
// ---------------------------------------------------------------------------
__global__ __launch_bounds__(512) void proj_mfma(
    const float* __restrict__ x,
    const unsigned short* __restrict__ whf,
    const unsigned short* __restrict__ wlf,
    unsigned short* __restrict__ qh, unsigned short* __restrict__ ql,
    unsigned short* __restrict__ kh, unsigned short* __restrict__ kl,
    unsigned short* __restrict__ vT)
{
    __shared__ unsigned short xh[64 * 64];   // 8 KB, swizzled
    __shared__ unsigned short xl[64 * 64];   // 8 KB, swizzled

    const int tid  = threadIdx.x;
    const int L    = tid & 63;
    const int w    = tid >> 6;               // wave id 0..7
    const int g    = L >> 4;
    const int l16  = L & 15;
    const int row0 = blockIdx.x * 64;
    const int mtb  = (w >> 2) * 2;           // m-tile base: 0 or 2
    const int ntgb = (w & 3) * 3;            // n-tile-group base: 0,3,6,9

    f32x4 acc[2][3];
#pragma unroll
    for (int mt = 0; mt < 2; ++mt)
#pragma unroll
        for (int nt = 0; nt < 3; ++nt)
#pragma unroll
            for (int r = 0; r < 4; ++r) acc[mt][nt][r] = 0.f;

    // staging: thread covers row srow, 8-elem chunk sc8
    const int srow = tid >> 3;               // 0..63
    const int sc8  = tid & 7;                // 0..7
    const float* xsrc = x + (size_t)(row0 + srow) * NE + sc8 * 8;
    const int soff = srow * 64 + ((sc8 ^ (srow & 7)) << 3);

    // prefetch ks = 0
    float4 p0 = *reinterpret_cast<const float4*>(xsrc);
    float4 p1 = *reinterpret_cast<const float4*>(xsrc + 4);

    for (int ks = 0; ks < 16; ++ks) {        // K loop, BK = 64
        __syncthreads();                     // prior-step LDS reads done
        {
            float xv[8];
            xv[0]=p0.x; xv[1]=p0.y; xv[2]=p0.z; xv[3]=p0.w;
            xv[4]=p1.x; xv[5]=p1.y; xv[6]=p1.z; xv[7]=p1.w;
            bf16x8 hv, lv;
#pragma unroll
            for (int j = 0; j < 8; ++j) {
                const unsigned short hb = f2b(xv[j]);
                const unsigned short lb = f2b(xv[j] - b2f(hb));
                hv[j] = (short)hb;
                lv[j] = (short)lb;
            }
            *reinterpret_cast<bf16x8*>(&xh[soff]) = hv;
            *reinterpret_cast<bf16x8*>(&xl[soff]) = lv;
        }
        if (ks < 15) {                       // prefetch next subtile
            p0 = *reinterpret_cast<const float4*>(xsrc + (ks + 1) * 64);
            p1 = *reinterpret_cast<const float4*>(xsrc + (ks + 1) * 64 + 4);
        }
        __syncthreads();

#pragma unroll
        for (int kc = 0; kc < 2; ++kc) {
            bf16x8 ah[2], al[2];
#pragma unroll
            for (int mt = 0; mt < 2; ++mt) {
                const int r    = (mtb + mt) * 16 + l16;
                const int kb16 = kc * 4 + g;
                const int off  = r * 64 + ((kb16 ^ (r & 7)) << 3);
                ah[mt] = *reinterpret_cast<const bf16x8*>(&xh[off]);
                al[mt] = *reinterpret_cast<const bf16x8*>(&xl[off]);
            }
#pragma unroll
            for (int nt = 0; nt < 3; ++nt) {
                const size_t fidx =
                    ((size_t)((ntgb + nt) * 32 + (ks * 2 + kc))) * 64 + L;
                const bf16x8 bh = *reinterpret_cast<const bf16x8*>(whf + fidx * 8);
                const bf16x8 bl = *reinterpret_cast<const bf16x8*>(wlf + fidx * 8);
#pragma unroll
                for (int mt = 0; mt < 2; ++mt) {
                    acc[mt][nt] = __builtin_amdgcn_mfma_f32_16x16x32_bf16(
                        ah[mt], bh, acc[mt][nt], 0, 0, 0);
                    acc[mt][nt] = __builtin_amdgcn_mfma_f32_16x16x32_bf16(
                        ah[mt], bl, acc[mt][nt], 0, 0, 0);
                    acc[mt][nt] = __builtin_amdgcn_mfma_f32_16x16x32_bf16(
                        al[mt], bh, acc[mt][nt], 0, 0, 0);
                }
            }
        }
    }

    // epilogue: C/D layout col=L&15, row=(L>>4)*4+reg
#pragma unroll
    for (int nt = 0; nt < 3; ++nt) {
        const int gc0 = (ntgb + nt) * 16;
        const int lc  = l16;
#pragma unroll
        for (int mt = 0; mt < 2; ++mt) {
            const int t0g = row0 + (mtb + mt) * 16 + g * 4;   // row of reg 0
            if (gc0 < 128) {
                unsigned short* dh = (gc0 < 64) ? qh : kh;
                unsigned short* dl = (gc0 < 64) ? ql : kl;
                const int col = (gc0 & 63) + lc;
#pragma unroll
                for (int reg = 0; reg < 4; ++reg) {
                    const float val = acc[mt][nt][reg];
                    const unsigned short hb = f2b(val);
                    const unsigned short lb = f2b(val - b2f(hb));
                    dh[(size_t)(t0g + reg) * HS + col] = hb;
                    dl[(size_t)(t0g + reg) * HS + col] = lb;
                }
            } else {
                const int col  = (gc0 - 128) + lc;   // h index
                const int bat  = t0g >> 11;
                const int tloc = t0g & 2047;
                ushort4 pk;
                unsigned short* pp = reinterpret_cast<unsigned short*>(&pk);
#pragma unroll
                for (int reg = 0; reg < 4; ++reg)
                    pp[reg] = f2b(acc[mt][nt][reg]);
                *reinterpret_cast<ushort4*>(
                    &vT[((size_t)bat * HS + col) * TT + tloc]) = pk;
            }
        }
    }
}

// ---------------------------------------------------------------------------
// Kernel 2: MFMA causal attention, QBLK=32 rows/block, 512 thr = 8 waves.
// Zero region of A (cols >= E) written with plain coalesced stores at the
// TOP of the kernel (retires during compute). Wave w owns score col-tiles
// w+8i (acc[16][2] f32x4). Softmax via shfl + LDS cross-wave reduce.
// P (normalized bf16, swizzled) in 128 KB LDS. After one barrier: PV
// (wave-private out tile, MFMA with vT B-frags from L2), then plain
// coalesced A value writes (cols < E) from P.
// ---------------------------------------------------------------------------
__global__ __launch_bounds__(512, 2) void attn_mfma(
    const unsigned short* __restrict__ qh, const unsigned short* __restrict__ ql,
    const unsigned short* __restrict__ kh, const unsigned short* __restrict__ kl,
    const unsigned short* __restrict__ vT,
    float* __restrict__ A, float* __restrict__ out)
{
    __shared__ unsigned short P[32 * TT];    // 128 KB, 16B-chunk XOR swizzle
    __shared__ float redm[8][32];
    __shared__ float reds[8][32];
    __shared__ float mrow[32];
    __shared__ float sinv[32];

    const int tid = threadIdx.x;
    const int L   = tid & 63;
    const int w   = tid >> 6;                // wave 0..7
    const int b   = blockIdx.x & 7;          // batch == XCD slot
    const int qt  = 63 - (blockIdx.x >> 3);  // longest first
    const int Q0  = qt * 32;
    const int E   = Q0 + 32;                 // causal extent (mult of 32)
    const int g   = L >> 4;
    const int l16 = L & 15;
    const size_t tbase = (size_t)b * TT;

    // ---- early zero-fill of A (cols >= E): overlaps all compute ----
    {
        f32x4 z;
        z[0] = 0.f; z[1] = 0.f; z[2] = 0.f; z[3] = 0.f;
#pragma unroll
        for (int rr = 0; rr < 4; ++rr) {
            const int row = 4 * w + rr;
            float* arow = A + (tbase + Q0 + row) * TT;
            for (int c0 = (E >> 8) << 8; c0 < TT; c0 += 256) {
                const int col = c0 + 4 * L;
                if (col >= E)
                    *reinterpret_cast<f32x4*>(arow + col) = z;
            }
        }
    }

    // ---- Q fragments (hi/lo) ----
    bf16x8 qfh[2][2], qfl[2][2];             // [rowtile][kchunk]
#pragma unroll
    for (int rt = 0; rt < 2; ++rt)
#pragma unroll
        for (int kc = 0; kc < 2; ++kc) {
            const size_t off = (tbase + Q0 + rt * 16 + l16) * HS + kc * 32 + g * 8;
            qfh[rt][kc] = *reinterpret_cast<const bf16x8*>(qh + off);
            qfl[rt][kc] = *reinterpret_cast<const bf16x8*>(ql + off);
        }

    // ---- QK^T (split bf16: hh + hl + lh) ----
    f32x4 acc[16][2];
#pragma unroll
    for (int i = 0; i < 16; ++i)
#pragma unroll
        for (int rt = 0; rt < 2; ++rt)
#pragma unroll
            for (int r = 0; r < 4; ++r) acc[i][rt][r] = 0.f;

#pragma unroll
    for (int i = 0; i < 16; ++i) {
        const int k0 = (w + 8 * i) * 16;
        if (k0 < E) {
#pragma unroll
            for (int kc = 0; kc < 2; ++kc) {
                const size_t koff = (tbase + k0 + l16) * HS + kc * 32 + g * 8;
                const bf16x8 bh = *reinterpret_cast<const bf16x8*>(kh + koff);
                const bf16x8 bl = *reinterpret_cast<const bf16x8*>(kl + koff);
#pragma unroll
                for (int rt = 0; rt < 2; ++rt) {
                    acc[i][rt] = __builtin_amdgcn_mfma_f32_16x16x32_bf16(
                        qfh[rt][kc], bh, acc[i][rt], 0, 0, 0);
                    acc[i][rt] = __builtin_amdgcn_mfma_f32_16x16x32_bf16(
                        qfh[rt][kc], bl, acc[i][rt], 0, 0, 0);
                    acc[i][rt] = __builtin_amdgcn_mfma_f32_16x16x32_bf16(
                        qfl[rt][kc], bh, acc[i][rt], 0, 0, 0);
                }
            }
        }
    }

    // ---- causal mask + per-lane partial row max ----
    float pm[2][4];
#pragma unroll
    for (int rt = 0; rt < 2; ++rt)
#pragma unroll
        for (int r = 0; r < 4; ++r) pm[rt][r] = -3e38f;

#pragma unroll
    for (int i = 0; i < 16; ++i) {
        const int k0 = (w + 8 * i) * 16;
        if (k0 < E) {
            const int col = k0 + l16;
#pragma unroll
            for (int rt = 0; rt < 2; ++rt) {
                const int row = Q0 + rt * 16 + g * 4;
#pragma unroll
                for (int r = 0; r < 4; ++r) {
                    float s = acc[i][rt][r];
                    s = (col > row + r) ? -3e38f : s;
                    acc[i][rt][r] = s;
                    pm[rt][r] = fmaxf(pm[rt][r], s);
                }
            }
        }
    }
#pragma unroll
    for (int m = 1; m < 16; m <<= 1)
#pragma unroll
        for (int rt = 0; rt < 2; ++rt)
#pragma unroll
            for (int r = 0; r < 4; ++r)
                pm[rt][r] = fmaxf(pm[rt][r], __shfl_xor(pm[rt][r], m, 64));
    if (l16 == 0)
#pragma unroll
        for (int rt = 0; rt < 2; ++rt)
#pragma unroll
            for (int r = 0; r < 4; ++r)
                redm[w][rt * 16 + g * 4 + r] = pm[rt][r];
    __syncthreads();
    if (tid < 32) {
        float m = -3e38f;
#pragma unroll
        for (int ww = 0; ww < 8; ++ww) m = fmaxf(m, redm[ww][tid]);
        mrow[tid] = m;
    }
    __syncthreads();
    float mr[2][4];
#pragma unroll
    for (int rt = 0; rt < 2; ++rt)
#pragma unroll
        for (int r = 0; r < 4; ++r) mr[rt][r] = mrow[rt * 16 + g * 4 + r];

    // ---- exp (f32, in regs) + partial row sums ----
    float ps[2][4];
#pragma unroll
    for (int rt = 0; rt < 2; ++rt)
#pragma unroll
        for (int r = 0; r < 4; ++r) ps[rt][r] = 0.f;

#pragma unroll
    for (int i = 0; i < 16; ++i) {
        const int k0 = (w + 8 * i) * 16;
        if (k0 < E) {
#pragma unroll
            for (int rt = 0; rt < 2; ++rt)
#pragma unroll
                for (int r = 0; r < 4; ++r) {
                    const float e = __expf(acc[i][rt][r] - mr[rt][r]);
                    acc[i][rt][r] = e;
                    ps[rt][r] += e;
                }
        }
    }
#pragma unroll
    for (int m = 1; m < 16; m <<= 1)
#pragma unroll
        for (int rt = 0; rt < 2; ++rt)
#pragma unroll
            for (int r = 0; r < 4; ++r)
                ps[rt][r] += __shfl_xor(ps[rt][r], m, 64);
    if (l16 == 0)
#pragma unroll
        for (int rt = 0; rt < 2; ++rt)
#pragma unroll
            for (int r = 0; r < 4; ++r)
                reds[w][rt * 16 + g * 4 + r] = ps[rt][r];
    __syncthreads();
    if (tid < 32) {
        float s = 0.f;
#pragma unroll
        for (int ww = 0; ww < 8; ++ww) s += reds[ww][tid];
        sinv[tid] = 1.f / s;
    }
    __syncthreads();
    float iv[2][4];
#pragma unroll
    for (int rt = 0; rt < 2; ++rt)
#pragma unroll
        for (int r = 0; r < 4; ++r) iv[rt][r] = sinv[rt * 16 + g * 4 + r];

    // ---- write P (normalized bf16, swizzled LDS) ----
#pragma unroll
    for (int i = 0; i < 16; ++i) {
        const int k0 = (w + 8 * i) * 16;
        if (k0 < E) {
            const int col   = k0 + l16;
            const int chunk = col >> 3;
            const int cl    = col & 7;
#pragma unroll
            for (int rt = 0; rt < 2; ++rt) {
                const int lrow = rt * 16 + g * 4;
#pragma unroll
                for (int r = 0; r < 4; ++r) {
                    const int row = lrow + r;
                    P[row * 2048 + ((chunk ^ (row & 7)) << 3) + cl] =
                        f2b(acc[i][rt][r] * iv[rt][r]);
                }
            }
        }
    }
    __syncthreads();

    // ---- PV: wave w owns out tile (rt_o = w>>2, ht = w&3); E%32==0 ----
    const int rt_o = w >> 2;
    const int ht   = w & 3;
    f32x4 oacc;
#pragma unroll
    for (int r = 0; r < 4; ++r) oacc[r] = 0.f;

    const int nkk = E >> 5;
    const unsigned short* vbase = vT + ((size_t)b * HS + ht * 16 + l16) * TT;
    const int prow = rt_o * 16 + l16;
    for (int kk = 0; kk < nkk; ++kk) {
        const int chunk = kk * 4 + g;
        const bf16x8 pa = *reinterpret_cast<const bf16x8*>(
            &P[prow * 2048 + ((chunk ^ (prow & 7)) << 3)]);
        const bf16x8 vb =
            *reinterpret_cast<const bf16x8*>(vbase + kk * 32 + g * 8);
        oacc = __builtin_amdgcn_mfma_f32_16x16x32_bf16(pa, vb, oacc, 0, 0, 0);
    }
#pragma unroll
    for (int r = 0; r < 4; ++r)
        out[(tbase + Q0 + rt_o * 16 + g * 4 + r) * HS + ht * 16 + l16] =
            oacc[r];

    // ---- A value write: plain coalesced f32 pass from P (cols < E) ----
#pragma unroll
    for (int rr = 0; rr < 4; ++rr) {
        const int row = 4 * w + rr;
        float* arow = A + (tbase + Q0 + row) * TT;
        for (int c0 = 0; c0 < E; c0 += 256) {
            const int col = c0 + 4 * L;
            if (col < E) {                    // col%4==0, E%32==0 -> col+3 < E
                const int chunk = col >> 3;
                const ushort4 pk = *reinterpret_cast<const ushort4*>(
                    &P[row * 2048 + ((chunk ^ (row & 7)) << 3) + (col & 7)]);
                f32x4 o;
                o[0] = b2f(pk.x); o[1] = b2f(pk.y);
                o[2] = b2f(pk.z); o[3] = b2f(pk.w);
                *reinterpret_cast<f32x4*>(arow + col) = o;
            }
        }
    }
}

// ---------------------------------------------------------------------------
extern "C" void kernel_launch(void* const* d_in, const int* in_sizes, int n_in,
                              void* d_out, int out_size, void* d_ws,
                              size_t ws_size, hipStream_t stream)
{
    (void)in_sizes; (void)n_in; (void)out_size; (void)ws_size;

    // setup_inputs() dict order: x, Wk, Wq, Wv
    const float* x  = (const float*)d_in[0];
    const float* Wk = (const float*)d_in[1];
    const float* Wq = (const float*)d_in[2];
    const float* Wv = (const float*)d_in[3];

    float* A   = (float*)d_out;                         // (B,T,T)
    float* out = A + (size_t)BB * TT * TT;              // (B,T,H)

    // workspace: 5 bf16 arrays of B*T*H + W fragments  (10.75 MB total)
    const size_t NTH = (size_t)BB * TT * HS;            // 1048576
    unsigned short* qh  = (unsigned short*)d_ws;
    unsigned short* ql  = qh + NTH;
    unsigned short* kh  = ql + NTH;
    unsigned short* kl  = kh + NTH;
    unsigned short* vT  = kl + NTH;
    unsigned short* whf = vT + NTH;
    unsigned short* wlf = whf + (size_t)24576 * 8;

    wprep_kernel<<<96, 256, 0, stream>>>(Wq, Wk, Wv, whf, wlf);
    proj_mfma<<<256, 512, 0, stream>>>(x, whf, wlf, qh, ql, kh, kl, vT);
    attn_mfma<<<BB * (TT / 32), 512, 0, stream>>>(qh, ql, kh, kl, vT, A, out);
}

// Round 8
// 105.501 us; speedup vs baseline: 1.1891x; 1.1180x over previous
//
#include <hip/hip_runtime.h>
#include <cstdint>
#include <cstddef>

#define NE 1024   // embedding dim
#define HS 64     // head size
#define TT 2048   // sequence length
#define BB 8      // batch

typedef short bf16x8 __attribute__((ext_vector_type(8)));
typedef float f32x4  __attribute__((ext_vector_type(4)));

// round-to-nearest-even f32 -> bf16 (bit pattern as ushort)
__device__ __forceinline__ unsigned short f2b(float f) {
    union { float f; uint32_t u; } v; v.f = f;
    uint32_t r = v.u + 0x7fffu + ((v.u >> 16) & 1u);
    return (unsigned short)(r >> 16);
}
__device__ __forceinline__ float b2f(unsigned short b) {
    union { uint32_t u; float f; } v; v.u = ((uint32_t)b) << 16;
    return v.f;
}

// ---------------------------------------------------------------------------
// Kernel 0: W = [Wq;Wk;Wv*0.125] (192x1024) -> MFMA B-fragments, split hi/lo.
// frag layout (16x16x32): lane L holds B[k=kcg*32+(L>>4)*8+j][col=ntg*16+(L&15)]
// ---------------------------------------------------------------------------
__global__ __launch_bounds__(256) void wprep_kernel(
    const float* __restrict__ Wq, const float* __restrict__ Wk,
    const float* __restrict__ Wv,
    unsigned short* __restrict__ whf, unsigned short* __restrict__ wlf)
{
    const int t   = blockIdx.x * 256 + threadIdx.x;   // 0..24575
    const int L   = t & 63;
    const int kcg = (t >> 6) & 31;
    const int ntg = t >> 11;                          // 0..11
    const int col = ntg * 16 + (L & 15);              // 0..191
    const int k0  = kcg * 32 + (L >> 4) * 8;

    const float* W;
    float scale = 1.f;
    if (col < 64)        W = Wq + (size_t)col * NE;
    else if (col < 128)  W = Wk + (size_t)(col - 64) * NE;
    else               { W = Wv + (size_t)(col - 128) * NE; scale = 0.125f; }

    bf16x8 h, l;
#pragma unroll
    for (int j = 0; j < 8; ++j) {
        const float f = W[k0 + j] * scale;
        const unsigned short hb = f2b(f);
        const unsigned short lb = f2b(f - b2f(hb));
        h[j] = (short)hb;
        l[j] = (short)lb;
    }
    *reinterpret_cast<bf16x8*>(whf + (size_t)t * 8) = h;
    *reinterpret_cast<bf16x8*>(wlf + (size_t)t * 8) = l;
}

// ---------------------------------------------------------------------------
// Kernel 1: projections via split-bf16 MFMA.
// BM=32, 256 threads = 4 waves, grid 512 -> 2 blocks/CU (4 waves/SIMD).
// Wave w owns n-tile group w*3 (3 tiles) x 2 m-tiles (acc = 24 VGPR).
// Register prefetch of next x-subtile overlaps the MFMA phase.
// Outputs: qh/ql, kh/kl row-major bf16 (hi/lo split), vT [B][64][T] bf16.
// ---------------------------------------------------------------------------
__global__ __launch_bounds__(256) void proj_mfma(
    const float* __restrict__ x,
    const unsigned short* __restrict__ whf,
    const unsigned short* __restrict__ wlf,
    unsigned short* __restrict__ qh, unsigned short* __restrict__ ql,
    unsigned short* __restrict__ kh, unsigned short* __restrict__ kl,
    unsigned short* __restrict__ vT)
{
    __shared__ unsigned short xh[32 * 64];   // 4 KB, swizzled
    __shared__ unsigned short xl[32 * 64];   // 4 KB, swizzled

    const int tid  = threadIdx.x;
    const int L    = tid & 63;
    const int w    = tid >> 6;               // wave id 0..3
    const int g    = L >> 4;
    const int l16  = L & 15;
    const int row0 = blockIdx.x * 32;
    const int ntgb = w * 3;                  // n-tile-group base: 0,3,6,9

    f32x4 acc[2][3];
#pragma unroll
    for (int mt = 0; mt < 2; ++mt)
#pragma unroll
        for (int nt = 0; nt < 3; ++nt)
#pragma unroll
            for (int r = 0; r < 4; ++r) acc[mt][nt][r] = 0.f;

    // staging: thread covers row srow, 8-elem chunk sc8 (32x64 tile)
    const int srow = tid >> 3;               // 0..31
    const int sc8  = tid & 7;                // 0..7
    const float* xsrc = x + (size_t)(row0 + srow) * NE + sc8 * 8;
    const int soff = srow * 64 + ((sc8 ^ (srow & 7)) << 3);

    // prefetch ks = 0
    float4 p0 = *reinterpret_cast<const float4*>(xsrc);
    float4 p1 = *reinterpret_cast<const float4*>(xsrc + 4);

    for (int ks = 0; ks < 16; ++ks) {        // K loop, BK = 64
        __syncthreads();                     // prior-step LDS reads done
        {
            float xv[8];
            xv[0]=p0.x; xv[1]=p0.y; xv[2]=p0.z; xv[3]=p0.w;
            xv[4]=p1.x; xv[5]=p1.y; xv[6]=p1.z; xv[7]=p1.w;
            bf16x8 hv, lv;
#pragma unroll
            for (int j = 0; j < 8; ++j) {
                const unsigned short hb = f2b(xv[j]);
                const unsigned short lb = f2b(xv[j] - b2f(hb));
                hv[j] = (short)hb;
                lv[j] = (short)lb;
            }
            *reinterpret_cast<bf16x8*>(&xh[soff]) = hv;
            *reinterpret_cast<bf16x8*>(&xl[soff]) = lv;
        }
        if (ks < 15) {                       // prefetch next subtile
            p0 = *reinterpret_cast<const float4*>(xsrc + (ks + 1) * 64);
            p1 = *reinterpret_cast<const float4*>(xsrc + (ks + 1) * 64 + 4);
        }
        __syncthreads();

#pragma unroll
        for (int kc = 0; kc < 2; ++kc) {
            bf16x8 ah[2], al[2];
#pragma unroll
            for (int mt = 0; mt < 2; ++mt) {
                const int r    = mt * 16 + l16;
                const int kb16 = kc * 4 + g;
                const int off  = r * 64 + ((kb16 ^ (r & 7)) << 3);
                ah[mt] = *reinterpret_cast<const bf16x8*>(&xh[off]);
                al[mt] = *reinterpret_cast<const bf16x8*>(&xl[off]);
            }
#pragma unroll
            for (int nt = 0; nt < 3; ++nt) {
                const size_t fidx =
                    ((size_t)((ntgb + nt) * 32 + (ks * 2 + kc))) * 64 + L;
                const bf16x8 bh = *reinterpret_cast<const bf16x8*>(whf + fidx * 8);
                const bf16x8 bl = *reinterpret_cast<const bf16x8*>(wlf + fidx * 8);
#pragma unroll
                for (int mt = 0; mt < 2; ++mt) {
                    acc[mt][nt] = __builtin_amdgcn_mfma_f32_16x16x32_bf16(
                        ah[mt], bh, acc[mt][nt], 0, 0, 0);
                    acc[mt][nt] = __builtin_amdgcn_mfma_f32_16x16x32_bf16(
                        ah[mt], bl, acc[mt][nt], 0, 0, 0);
                    acc[mt][nt] = __builtin_amdgcn_mfma_f32_16x16x32_bf16(
                        al[mt], bh, acc[mt][nt], 0, 0, 0);
                }
            }
        }
    }

    // epilogue: C/D layout col=L&15, row=(L>>4)*4+reg
#pragma unroll
    for (int nt = 0; nt < 3; ++nt) {
        const int gc0 = (ntgb + nt) * 16;
        const int lc  = l16;
#pragma unroll
        for (int mt = 0; mt < 2; ++mt) {
            const int t0g = row0 + mt * 16 + g * 4;   // row of reg 0
            if (gc0 < 128) {
                unsigned short* dh = (gc0 < 64) ? qh : kh;
                unsigned short* dl = (gc0 < 64) ? ql : kl;
                const int col = (gc0 & 63) + lc;
#pragma unroll
                for (int reg = 0; reg < 4; ++reg) {
                    const float val = acc[mt][nt][reg];
                    const unsigned short hb = f2b(val);
                    const unsigned short lb = f2b(val - b2f(hb));
                    dh[(size_t)(t0g + reg) * HS + col] = hb;
                    dl[(size_t)(t0g + reg) * HS + col] = lb;
                }
            } else {
                const int col  = (gc0 - 128) + lc;   // h index
                const int bat  = t0g >> 11;
                const int tloc = t0g & 2047;
                ushort4 pk;
                unsigned short* pp = reinterpret_cast<unsigned short*>(&pk);
#pragma unroll
                for (int reg = 0; reg < 4; ++reg)
                    pp[reg] = f2b(acc[mt][nt][reg]);
                *reinterpret_cast<ushort4*>(
                    &vT[((size_t)bat * HS + col) * TT + tloc]) = pk;
            }
        }
    }
}

// ---------------------------------------------------------------------------
// Kernel 2: MFMA causal attention, QBLK=32 rows/block, 512 thr = 8 waves.
// (unchanged from round 7)
// ---------------------------------------------------------------------------
__global__ __launch_bounds__(512, 2) void attn_mfma(
    const unsigned short* __restrict__ qh, const unsigned short* __restrict__ ql,
    const unsigned short* __restrict__ kh, const unsigned short* __restrict__ kl,
    const unsigned short* __restrict__ vT,
    float* __restrict__ A, float* __restrict__ out)
{
    __shared__ unsigned short P[32 * TT];    // 128 KB, 16B-chunk XOR swizzle
    __shared__ float redm[8][32];
    __shared__ float reds[8][32];
    __shared__ float mrow[32];
    __shared__ float sinv[32];

    const int tid = threadIdx.x;
    const int L   = tid & 63;
    const int w   = tid >> 6;                // wave 0..7
    const int b   = blockIdx.x & 7;          // batch == XCD slot
    const int qt  = 63 - (blockIdx.x >> 3);  // longest first
    const int Q0  = qt * 32;
    const int E   = Q0 + 32;                 // causal extent (mult of 32)
    const int g   = L >> 4;
    const int l16 = L & 15;
    const size_t tbase = (size_t)b * TT;

    // ---- early zero-fill of A (cols >= E): overlaps all compute ----
    {
        f32x4 z;
        z[0] = 0.f; z[1] = 0.f; z[2] = 0.f; z[3] = 0.f;
#pragma unroll
        for (int rr = 0; rr < 4; ++rr) {
            const int row = 4 * w + rr;
            float* arow = A + (tbase + Q0 + row) * TT;
            for (int c0 = (E >> 8) << 8; c0 < TT; c0 += 256) {
                const int col = c0 + 4 * L;
                if (col >= E)
                    *reinterpret_cast<f32x4*>(arow + col) = z;
            }
        }
    }

    // ---- Q fragments (hi/lo) ----
    bf16x8 qfh[2][2], qfl[2][2];             // [rowtile][kchunk]
#pragma unroll
    for (int rt = 0; rt < 2; ++rt)
#pragma unroll
        for (int kc = 0; kc < 2; ++kc) {
            const size_t off = (tbase + Q0 + rt * 16 + l16) * HS + kc * 32 + g * 8;
            qfh[rt][kc] = *reinterpret_cast<const bf16x8*>(qh + off);
            qfl[rt][kc] = *reinterpret_cast<const bf16x8*>(ql + off);
        }

    // ---- QK^T (split bf16: hh + hl + lh) ----
    f32x4 acc[16][2];
#pragma unroll
    for (int i = 0; i < 16; ++i)
#pragma unroll
        for (int rt = 0; rt < 2; ++rt)
#pragma unroll
            for (int r = 0; r < 4; ++r) acc[i][rt][r] = 0.f;

#pragma unroll
    for (int i = 0; i < 16; ++i) {
        const int k0 = (w + 8 * i) * 16;
        if (k0 < E) {
#pragma unroll
            for (int kc = 0; kc < 2; ++kc) {
                const size_t koff = (tbase + k0 + l16) * HS + kc * 32 + g * 8;
                const bf16x8 bh = *reinterpret_cast<const bf16x8*>(kh + koff);
                const bf16x8 bl = *reinterpret_cast<const bf16x8*>(kl + koff);
#pragma unroll
                for (int rt = 0; rt < 2; ++rt) {
                    acc[i][rt] = __builtin_amdgcn_mfma_f32_16x16x32_bf16(
                        qfh[rt][kc], bh, acc[i][rt], 0, 0, 0);
                    acc[i][rt] = __builtin_amdgcn_mfma_f32_16x16x32_bf16(
                        qfh[rt][kc], bl, acc[i][rt], 0, 0, 0);
                    acc[i][rt] = __builtin_amdgcn_mfma_f32_16x16x32_bf16(
                        qfl[rt][kc], bh, acc[i][rt], 0, 0, 0);
                }
            }
        }
    }

    // ---- causal mask + per-lane partial row max ----
    float pm[2][4];
#pragma unroll
    for (int rt = 0; rt < 2; ++rt)
#pragma unroll
        for (int r = 0; r < 4; ++r) pm[rt][r] = -3e38f;

#pragma unroll
    for (int i = 0; i < 16; ++i) {
        const int k0 = (w + 8 * i) * 16;
        if (k0 < E) {
            const int col = k0 + l16;
#pragma unroll
            for (int rt = 0; rt < 2; ++rt) {
                const int row = Q0 + rt * 16 + g * 4;
#pragma unroll
                for (int r = 0; r < 4; ++r) {
                    float s = acc[i][rt][r];
                    s = (col > row + r) ? -3e38f : s;
                    acc[i][rt][r] = s;
                    pm[rt][r] = fmaxf(pm[rt][r], s);
                }
            }
        }
    }
#pragma unroll
    for (int m = 1; m < 16; m <<= 1)
#pragma unroll
        for (int rt = 0; rt < 2; ++rt)
#pragma unroll
            for (int r = 0; r < 4; ++r)
                pm[rt][r] = fmaxf(pm[rt][r], __shfl_xor(pm[rt][r], m, 64));
    if (l16 == 0)
#pragma unroll
        for (int rt = 0; rt < 2; ++rt)
#pragma unroll
            for (int r = 0; r < 4; ++r)
                redm[w][rt * 16 + g * 4 + r] = pm[rt][r];
    __syncthreads();
    if (tid < 32) {
        float m = -3e38f;
#pragma unroll
        for (int ww = 0; ww < 8; ++ww) m = fmaxf(m, redm[ww][tid]);
        mrow[tid] = m;
    }
    __syncthreads();
    float mr[2][4];
#pragma unroll
    for (int rt = 0; rt < 2; ++rt)
#pragma unroll
        for (int r = 0; r < 4; ++r) mr[rt][r] = mrow[rt * 16 + g * 4 + r];

    // ---- exp (f32, in regs) + partial row sums ----
    float ps[2][4];
#pragma unroll
    for (int rt = 0; rt < 2; ++rt)
#pragma unroll
        for (int r = 0; r < 4; ++r) ps[rt][r] = 0.f;

#pragma unroll
    for (int i = 0; i < 16; ++i) {
        const int k0 = (w + 8 * i) * 16;
        if (k0 < E) {
#pragma unroll
            for (int rt = 0; rt < 2; ++rt)
#pragma unroll
                for (int r = 0; r < 4; ++r) {
                    const float e = __expf(acc[i][rt][r] - mr[rt][r]);
                    acc[i][rt][r] = e;
                    ps[rt][r] += e;
                }
        }
    }
#pragma unroll
    for (int m = 1; m < 16; m <<= 1)
#pragma unroll
        for (int rt = 0; rt < 2; ++rt)
#pragma unroll
            for (int r = 0; r < 4; ++r)
                ps[rt][r] += __shfl_xor(ps[rt][r], m, 64);
    if (l16 == 0)
#pragma unroll
        for (int rt = 0; rt < 2; ++rt)
#pragma unroll
            for (int r = 0; r < 4; ++r)
                reds[w][rt * 16 + g * 4 + r] = ps[rt][r];
    __syncthreads();
    if (tid < 32) {
        float s = 0.f;
#pragma unroll
        for (int ww = 0; ww < 8; ++ww) s += reds[ww][tid];
        sinv[tid] = 1.f / s;
    }
    __syncthreads();
    float iv[2][4];
#pragma unroll
    for (int rt = 0; rt < 2; ++rt)
#pragma unroll
        for (int r = 0; r < 4; ++r) iv[rt][r] = sinv[rt * 16 + g * 4 + r];

    // ---- write P (normalized bf16, swizzled LDS) ----
#pragma unroll
    for (int i = 0; i < 16; ++i) {
        const int k0 = (w + 8 * i) * 16;
        if (k0 < E) {
            const int col   = k0 + l16;
            const int chunk = col >> 3;
            const int cl    = col & 7;
#pragma unroll
            for (int rt = 0; rt < 2; ++rt) {
                const int lrow = rt * 16 + g * 4;
#pragma unroll
                for (int r = 0; r < 4; ++r) {
                    const int row = lrow + r;
                    P[row * 2048 + ((chunk ^ (row & 7)) << 3) + cl] =
                        f2b(acc[i][rt][r] * iv[rt][r]);
                }
            }
        }
    }
    __syncthreads();

    // ---- PV: wave w owns out tile (rt_o = w>>2, ht = w&3); E%32==0 ----
    const int rt_o = w >> 2;
    const int ht   = w & 3;
    f32x4 oacc;
#pragma unroll
    for (int r = 0; r < 4; ++r) oacc[r] = 0.f;

    const int nkk = E >> 5;
    const unsigned short* vbase = vT + ((size_t)b * HS + ht * 16 + l16) * TT;
    const int prow = rt_o * 16 + l16;
    for (int kk = 0; kk < nkk; ++kk) {
        const int chunk = kk * 4 + g;
        const bf16x8 pa = *reinterpret_cast<const bf16x8*>(
            &P[prow * 2048 + ((chunk ^ (prow & 7)) << 3)]);
        const bf16x8 vb =
            *reinterpret_cast<const bf16x8*>(vbase + kk * 32 + g * 8);
        oacc = __builtin_amdgcn_mfma_f32_16x16x32_bf16(pa, vb, oacc, 0, 0, 0);
    }
#pragma unroll
    for (int r = 0; r < 4; ++r)
        out[(tbase + Q0 + rt_o * 16 + g * 4 + r) * HS + ht * 16 + l16] =
            oacc[r];

    // ---- A value write: plain coalesced f32 pass from P (cols < E) ----
#pragma unroll
    for (int rr = 0; rr < 4; ++rr) {
        const int row = 4 * w + rr;
        float* arow = A + (tbase + Q0 + row) * TT;
        for (int c0 = 0; c0 < E; c0 += 256) {
            const int col = c0 + 4 * L;
            if (col < E) {                    // col%4==0, E%32==0 -> col+3 < E
                const int chunk = col >> 3;
                const ushort4 pk = *reinterpret_cast<const ushort4*>(
                    &P[row * 2048 + ((chunk ^ (row & 7)) << 3) + (col & 7)]);
                f32x4 o;
                o[0] = b2f(pk.x); o[1] = b2f(pk.y);
                o[2] = b2f(pk.z); o[3] = b2f(pk.w);
                *reinterpret_cast<f32x4*>(arow + col) = o;
            }
        }
    }
}

// ---------------------------------------------------------------------------
extern "C" void kernel_launch(void* const* d_in, const int* in_sizes, int n_in,
                              void* d_out, int out_size, void* d_ws,
                              size_t ws_size, hipStream_t stream)
{
    (void)in_sizes; (void)n_in; (void)out_size; (void)ws_size;

    // setup_inputs() dict order: x, Wk, Wq, Wv
    const float* x  = (const float*)d_in[0];
    const float* Wk = (const float*)d_in[1];
    const float* Wq = (const float*)d_in[2];
    const float* Wv = (const float*)d_in[3];

    float* A   = (float*)d_out;                         // (B,T,T)
    float* out = A + (size_t)BB * TT * TT;              // (B,T,H)

    // workspace: 5 bf16 arrays of B*T*H + W fragments  (10.75 MB total)
    const size_t NTH = (size_t)BB * TT * HS;            // 1048576
    unsigned short* qh  = (unsigned short*)d_ws;
    unsigned short* ql  = qh + NTH;
    unsigned short* kh  = ql + NTH;
    unsigned short* kl  = kh + NTH;
    unsigned short* vT  = kl + NTH;
    unsigned short* whf = vT + NTH;
    unsigned short* wlf = whf + (size_t)24576 * 8;

    wprep_kernel<<<96, 256, 0, stream>>>(Wq, Wk, Wv, whf, wlf);
    proj_mfma<<<512, 256, 0, stream>>>(x, whf, wlf, qh, ql, kh, kl, vT);
    attn_mfma<<<BB * (TT / 32), 512, 0, stream>>>(qh, ql, kh, kl, vT, A, out);
}